// Round 1
// baseline (395.300 us; speedup 1.0000x reference)
//
#include <hip/hip_runtime.h>
#include <hip/hip_bf16.h>

// Problem: StyleLoss — x (1,512,64,64) fp32, target (512,256,256) fp32 -> scalar loss.
// loss = mean_{i,a,b}( (g_full[(i+a)%512,(i+b)%512]/2^20 - target[i,a,b])^2 ) * 1e6
// g_full = feats @ feats^T, feats = x reshaped (512, 4096).
//
// ws layout: [0, 4MB) bf16 feats (512*4096); [4MB, 5MB) fp32 g_full (512*512).

typedef __attribute__((ext_vector_type(8))) short bf16x8;   // 8 bf16 in 4 VGPRs
typedef __attribute__((ext_vector_type(4))) float f32x4;

#define CH 512
#define KDIM 4096
#define FEATS_ELEMS (CH * KDIM)

// ---------------------------------------------------------------- convert ----
__global__ __launch_bounds__(256) void convert_kernel(const float* __restrict__ x,
                                                      __hip_bfloat16* __restrict__ feats) {
    int idx = blockIdx.x * 256 + threadIdx.x;   // 262144 threads, 8 elems each
    const float4* x4 = (const float4*)x;
    float4 v0 = x4[idx * 2 + 0];
    float4 v1 = x4[idx * 2 + 1];
    float f[8] = {v0.x, v0.y, v0.z, v0.w, v1.x, v1.y, v1.z, v1.w};
    union { ushort u[8]; uint4 v; } o;
#pragma unroll
    for (int i = 0; i < 8; ++i) {
        __hip_bfloat16 b = __float2bfloat16(f[i]);
        o.u[i] = *reinterpret_cast<ushort*>(&b);
    }
    *reinterpret_cast<uint4*>(feats + idx * 8) = o.v;
}

// ---------------------------------------------------------------- gemm -------
// C = F * F^T, F is 512x4096 bf16 row-major. 64x64 block tile, BK=64,
// split-K=4 (gridDim.z), fp32 atomicAdd epilogue into zero-init g_full.
#define BM 64
#define BN 64
#define BK 64
#define LDT 72   // padded LDS stride in bf16: 144 B = 9*16 B (aligned, 2-way bank alias = free)

__global__ __launch_bounds__(256) void gemm_kernel(const __hip_bfloat16* __restrict__ feats,
                                                   float* __restrict__ g_full) {
    __shared__ __hip_bfloat16 a_tile[BM * LDT];
    __shared__ __hip_bfloat16 b_tile[BN * LDT];

    const int bm = blockIdx.x, bn = blockIdx.y, kz = blockIdx.z;
    const int tid  = threadIdx.x;
    const int lane = tid & 63;
    const int w    = tid >> 6;        // wave 0..3 -> M rows w*16..w*16+15
    const int m    = lane & 15;
    const int q    = lane >> 4;       // quad: k offset q*8

    const int srow = tid >> 3;        // staging: 0..31
    const int scol = (tid & 7) * 8;   // 0..56 step 8

    f32x4 acc[4] = {};                // 4 N-tiles of 16 cols each

    const int k0base = kz * (KDIM / 4);   // 1024 per split
    for (int kt = 0; kt < (KDIM / 4) / BK; ++kt) {   // 16 iters
        const int k0 = k0base + kt * BK;
#pragma unroll
        for (int p = 0; p < 2; ++p) {
            const int r = srow + p * 32;
            uint4 av = *(const uint4*)(feats + (size_t)(bm * 64 + r) * KDIM + k0 + scol);
            uint4 bv = *(const uint4*)(feats + (size_t)(bn * 64 + r) * KDIM + k0 + scol);
            uint* ap = (uint*)(a_tile + r * LDT + scol);
            ap[0] = av.x; ap[1] = av.y; ap[2] = av.z; ap[3] = av.w;
            uint* bp = (uint*)(b_tile + r * LDT + scol);
            bp[0] = bv.x; bp[1] = bv.y; bp[2] = bv.z; bp[3] = bv.w;
        }
        __syncthreads();
#pragma unroll
        for (int ks = 0; ks < 2; ++ks) {
            const int kk = ks * 32 + q * 8;
            bf16x8 afrag = *(const bf16x8*)(a_tile + (w * 16 + m) * LDT + kk);
#pragma unroll
            for (int j = 0; j < 4; ++j) {
                bf16x8 bfrag = *(const bf16x8*)(b_tile + (j * 16 + m) * LDT + kk);
                acc[j] = __builtin_amdgcn_mfma_f32_16x16x32_bf16(afrag, bfrag, acc[j], 0, 0, 0);
            }
        }
        __syncthreads();
    }

    // Epilogue: C/D layout col = lane&15, row = (lane>>4)*4 + reg (verified m89/m91)
    const int col = lane & 15;
    const int rq  = (lane >> 4) * 4;
#pragma unroll
    for (int j = 0; j < 4; ++j) {
#pragma unroll
        for (int reg = 0; reg < 4; ++reg) {
            const int rg = bm * 64 + w * 16 + rq + reg;
            const int cg = bn * 64 + j * 16 + col;
            atomicAdd(&g_full[rg * CH + cg], acc[j][reg]);
        }
    }
}

// ---------------------------------------------------------------- loss -------
// sum over t in [0, 512*256*256): (g_full[(i+a)&511,(i+b)&511]*gscale - target[t])^2
// t = i*65536 + a*256 + b. Vectorized 4 target elems (same row) per thread-iter.
__global__ __launch_bounds__(256) void loss_kernel(const float* __restrict__ target,
                                                   const float* __restrict__ g_full,
                                                   float* __restrict__ out) {
    const float gscale = 1.0f / 1048576.0f;          // 1/(b*local_ch*w*h)
    const float lscale = 1.0e6f / 33554432.0f;       // WEIGHT / count
    float acc = 0.0f;
    const int total4 = 512 * 256 * 256 / 4;          // 8388608
    for (int idx = blockIdx.x * 256 + threadIdx.x; idx < total4; idx += gridDim.x * 256) {
        const int t = idx << 2;
        const int i = t >> 16;
        const int a = (t >> 8) & 255;
        const int b = t & 255;
        const int row = (i + a) & 511;
        const float* grow = g_full + row * CH;
        const int c0 = i + b;                        // < 768
        float4 tv = ((const float4*)target)[idx];
        float g0 = grow[(c0 + 0) & 511];
        float g1 = grow[(c0 + 1) & 511];
        float g2 = grow[(c0 + 2) & 511];
        float g3 = grow[(c0 + 3) & 511];
        float d0 = __builtin_fmaf(g0, gscale, -tv.x);
        float d1 = __builtin_fmaf(g1, gscale, -tv.y);
        float d2 = __builtin_fmaf(g2, gscale, -tv.z);
        float d3 = __builtin_fmaf(g3, gscale, -tv.w);
        acc += d0 * d0 + d1 * d1 + d2 * d2 + d3 * d3;
    }
    // wave-64 butterfly reduce, then one atomic per wave
#pragma unroll
    for (int off = 32; off > 0; off >>= 1) acc += __shfl_xor(acc, off, 64);
    if ((threadIdx.x & 63) == 0) atomicAdd(out, acc * lscale);
}

// ---------------------------------------------------------------- launch -----
extern "C" void kernel_launch(void* const* d_in, const int* in_sizes, int n_in,
                              void* d_out, int out_size, void* d_ws, size_t ws_size,
                              hipStream_t stream) {
    const float* x      = (const float*)d_in[0];   // 2097152 fp32
    const float* target = (const float*)d_in[1];   // 33554432 fp32
    float* out = (float*)d_out;

    __hip_bfloat16* feats = (__hip_bfloat16*)d_ws;                       // 4 MB
    float* g_full = (float*)((char*)d_ws + FEATS_ELEMS * sizeof(__hip_bfloat16)); // 1 MB

    hipMemsetAsync(g_full, 0, CH * CH * sizeof(float), stream);
    hipMemsetAsync(d_out, 0, sizeof(float), stream);

    convert_kernel<<<FEATS_ELEMS / (256 * 8), 256, 0, stream>>>(x, feats);
    gemm_kernel<<<dim3(CH / BM, CH / BN, 4), 256, 0, stream>>>(feats, g_full);
    loss_kernel<<<4096, 256, 0, stream>>>(target, g_full, out);
}

// Round 2
// 278.857 us; speedup vs baseline: 1.4176x; 1.4176x over previous
//
#include <hip/hip_runtime.h>
#include <hip/hip_bf16.h>

// StyleLoss — x (1,512,64,64) fp32, target (512,256,256) fp32 -> scalar loss.
// loss = mean_{i,a,b}( (g_full[(i+a)%512,(i+b)%512]/2^20 - target[i,a,b])^2 ) * 1e6
// g_full = feats @ feats^T, feats = x reshaped (512, 4096), bf16 MFMA (tolerance ~2%).
//
// ws layout: [0, 4MB) bf16 feats (512*4096); [4MB, 5MB) fp32 g_full (512*512).

typedef __attribute__((ext_vector_type(8))) short bf16x8;   // 8 bf16 in 4 VGPRs
typedef __attribute__((ext_vector_type(4))) float f32x4;

#define CH 512
#define KDIM 4096
#define FEATS_ELEMS (CH * KDIM)

// ---------------------------------------------------------------- convert ----
__global__ __launch_bounds__(256) void convert_kernel(const float* __restrict__ x,
                                                      __hip_bfloat16* __restrict__ feats) {
    int idx = blockIdx.x * 256 + threadIdx.x;   // 262144 threads, 8 elems each
    const float4* x4 = (const float4*)x;
    float4 v0 = x4[idx * 2 + 0];
    float4 v1 = x4[idx * 2 + 1];
    float f[8] = {v0.x, v0.y, v0.z, v0.w, v1.x, v1.y, v1.z, v1.w};
    union { ushort u[8]; uint4 v; } o;
#pragma unroll
    for (int i = 0; i < 8; ++i) {
        __hip_bfloat16 b = __float2bfloat16(f[i]);
        o.u[i] = *reinterpret_cast<ushort*>(&b);
    }
    *reinterpret_cast<uint4*>(feats + idx * 8) = o.v;
}

// ---------------------------------------------------------------- gemm -------
// C = F * F^T, F is 512x4096 bf16 row-major. 64x64 block tile, BK=64,
// split-K=8 (gridDim.z -> 512 blocks, 2/CU), register-prefetch of next K-tile,
// fp32 atomicAdd epilogue into zero-init g_full.
#define BM 64
#define BK 64
#define SPLITK 8
#define LDT 72   // padded LDS stride in bf16: 144 B (b128-aligned, 2-way alias = free)

__global__ __launch_bounds__(256) void gemm_kernel(const __hip_bfloat16* __restrict__ feats,
                                                   float* __restrict__ g_full) {
    __shared__ __hip_bfloat16 a_tile[BM * LDT];
    __shared__ __hip_bfloat16 b_tile[BM * LDT];

    const int bm = blockIdx.x, bn = blockIdx.y, kz = blockIdx.z;
    const int tid  = threadIdx.x;
    const int lane = tid & 63;
    const int w    = tid >> 6;        // wave 0..3 -> M rows w*16..w*16+15
    const int m    = lane & 15;
    const int q    = lane >> 4;       // quad: k offset q*8

    const int srow = tid >> 3;        // staging row 0..31 (+32 for p=1)
    const int scol = (tid & 7) * 8;   // 0..56 step 8

    f32x4 acc[4] = {};                // 4 N-subtiles of 16 cols

    const int NT = (KDIM / SPLITK) / BK;            // 8 k-tiles per block
    const int k0base = kz * (KDIM / SPLITK);        // 512 per split

    const __hip_bfloat16* arow0 = feats + (size_t)(bm * 64 + srow) * KDIM + k0base + scol;
    const __hip_bfloat16* brow0 = feats + (size_t)(bn * 64 + srow) * KDIM + k0base + scol;

    uint4 pa[2], pb[2];
#pragma unroll
    for (int p = 0; p < 2; ++p) {
        pa[p] = *(const uint4*)(arow0 + (size_t)p * 32 * KDIM);
        pb[p] = *(const uint4*)(brow0 + (size_t)p * 32 * KDIM);
    }

    for (int kt = 0; kt < NT; ++kt) {
        if (kt > 0) __syncthreads();               // previous MFMA reads done
#pragma unroll
        for (int p = 0; p < 2; ++p) {
            uint* ap = (uint*)(a_tile + (srow + p * 32) * LDT + scol);
            ap[0] = pa[p].x; ap[1] = pa[p].y; ap[2] = pa[p].z; ap[3] = pa[p].w;
            uint* bp = (uint*)(b_tile + (srow + p * 32) * LDT + scol);
            bp[0] = pb[p].x; bp[1] = pb[p].y; bp[2] = pb[p].z; bp[3] = pb[p].w;
        }
        __syncthreads();
        if (kt + 1 < NT) {                         // prefetch next tile (overlaps MFMA)
            const int ko = (kt + 1) * BK;
#pragma unroll
            for (int p = 0; p < 2; ++p) {
                pa[p] = *(const uint4*)(arow0 + (size_t)p * 32 * KDIM + ko);
                pb[p] = *(const uint4*)(brow0 + (size_t)p * 32 * KDIM + ko);
            }
        }
#pragma unroll
        for (int ks = 0; ks < 2; ++ks) {
            const int kk = ks * 32 + q * 8;
            bf16x8 afrag = *(const bf16x8*)(a_tile + (w * 16 + m) * LDT + kk);
#pragma unroll
            for (int j = 0; j < 4; ++j) {
                bf16x8 bfrag = *(const bf16x8*)(b_tile + (j * 16 + m) * LDT + kk);
                acc[j] = __builtin_amdgcn_mfma_f32_16x16x32_bf16(afrag, bfrag, acc[j], 0, 0, 0);
            }
        }
    }

    // Epilogue: C/D layout col = lane&15, row = (lane>>4)*4 + reg (verified m89/m91)
    const int col = lane & 15;
    const int rq  = (lane >> 4) * 4;
#pragma unroll
    for (int j = 0; j < 4; ++j) {
#pragma unroll
        for (int reg = 0; reg < 4; ++reg) {
            const int rg = bm * 64 + w * 16 + rq + reg;
            const int cg = bn * 64 + j * 16 + col;
            atomicAdd(&g_full[rg * CH + cg], acc[j][reg]);
        }
    }
}

// ---------------------------------------------------------------- loss -------
// 2048 blocks; block covers contiguous 16384 target floats (i fixed = blk>>2).
// Per thread: 4 outer iters x 4 float4 target loads + 16 g gathers, all batched
// into registers BEFORE use -> ~20 loads in flight per wave (fixes the VGPR=12
// serialized-latency disease of round 1: 338 GB/s, VALUBusy 3.8%).
__global__ __launch_bounds__(256) void loss_kernel(const float* __restrict__ target,
                                                   const float* __restrict__ g_full,
                                                   float* __restrict__ out) {
    const float gscale = 1.0f / 1048576.0f;          // 1/(b*local_ch*w*h)
    const float lscale = 1.0e6f / 33554432.0f;       // WEIGHT / count

    const int tid  = threadIdx.x;
    const int lane = tid & 63;
    const int wv   = tid >> 6;
    const int blk  = blockIdx.x;
    const int i    = blk >> 2;                       // 4 blocks per i

    // column indices are the same for every row this thread touches
    int col[4];
#pragma unroll
    for (int n = 0; n < 4; ++n) col[n] = (i + 4 * lane + n) & 511;

    const float4* t4 = (const float4*)target;
    float acc = 0.0f;

#pragma unroll
    for (int j = 0; j < 4; ++j) {
        float4 tv[4];
        float  g[4][4];
#pragma unroll
        for (int k = 0; k < 4; ++k) {
            const int idx4 = blk * 4096 + j * 1024 + k * 256 + tid;
            tv[k] = t4[idx4];
            const int a   = (blk & 3) * 64 + j * 16 + k * 4 + wv;   // = (idx4>>6)&255
            const int row = (i + a) & 511;
            const float* grow = g_full + row * CH;
#pragma unroll
            for (int n = 0; n < 4; ++n) g[k][n] = grow[col[n]];
        }
#pragma unroll
        for (int k = 0; k < 4; ++k) {
            float d0 = __builtin_fmaf(g[k][0], gscale, -tv[k].x);
            float d1 = __builtin_fmaf(g[k][1], gscale, -tv[k].y);
            float d2 = __builtin_fmaf(g[k][2], gscale, -tv[k].z);
            float d3 = __builtin_fmaf(g[k][3], gscale, -tv[k].w);
            acc += d0 * d0 + d1 * d1 + d2 * d2 + d3 * d3;
        }
    }

    // wave-64 butterfly reduce, then one atomic per wave
#pragma unroll
    for (int off = 32; off > 0; off >>= 1) acc += __shfl_xor(acc, off, 64);
    if (lane == 0) atomicAdd(out, acc * lscale);
}

// ---------------------------------------------------------------- launch -----
extern "C" void kernel_launch(void* const* d_in, const int* in_sizes, int n_in,
                              void* d_out, int out_size, void* d_ws, size_t ws_size,
                              hipStream_t stream) {
    const float* x      = (const float*)d_in[0];   // 2097152 fp32
    const float* target = (const float*)d_in[1];   // 33554432 fp32
    float* out = (float*)d_out;

    __hip_bfloat16* feats = (__hip_bfloat16*)d_ws;                       // 4 MB
    float* g_full = (float*)((char*)d_ws + FEATS_ELEMS * sizeof(__hip_bfloat16)); // 1 MB

    hipMemsetAsync(g_full, 0, CH * CH * sizeof(float), stream);
    hipMemsetAsync(d_out, 0, sizeof(float), stream);

    convert_kernel<<<FEATS_ELEMS / (256 * 8), 256, 0, stream>>>(x, feats);
    gemm_kernel<<<dim3(CH / BM, CH / BM, SPLITK), 256, 0, stream>>>(feats, g_full);
    loss_kernel<<<2048, 256, 0, stream>>>(target, g_full, out);
}